// Round 4
// baseline (249.254 us; speedup 1.0000x reference)
//
#include <hip/hip_runtime.h>

typedef __attribute__((ext_vector_type(8))) short bhalf8;   // 8 bf16 MFMA operand
typedef __attribute__((ext_vector_type(4))) float f32x4;
typedef __attribute__((ext_vector_type(8))) unsigned short u16x8;
typedef __attribute__((ext_vector_type(4))) unsigned short u16x4;

#define BDIM 2
#define SDIM 2048
#define DDIM 1024
#define HDIM 16
#define HDHD 64

__device__ __forceinline__ unsigned short f2bf(float f) {
  unsigned u = __builtin_bit_cast(unsigned, f);
  u += 0x7fffu + ((u >> 16) & 1u);           // RNE
  return (unsigned short)(u >> 16);
}

// ---------------- elementwise f32 -> bf16 ----------------
__global__ __launch_bounds__(256) void cvt_hidden(const float* __restrict__ x,
                                                  unsigned short* __restrict__ y) {
  size_t i = ((size_t)blockIdx.x * 256 + threadIdx.x) * 4;
  f32x4 v = *(const f32x4*)(x + i);
  u16x4 o;
  o[0] = f2bf(v[0]); o[1] = f2bf(v[1]); o[2] = f2bf(v[2]); o[3] = f2bf(v[3]);
  *(u16x4*)(y + i) = o;
}

// ---------------- transpose + convert: W[R][C] f32 -> Wt[C][R] bf16 ----------------
__global__ __launch_bounds__(256) void transpose_cvt(const float* __restrict__ W,
                                                     unsigned short* __restrict__ Wt,
                                                     int R, int C) {
  __shared__ float tl[32][33];
  int rt = blockIdx.x * 32, ct = blockIdx.y * 32;
  int r8 = threadIdx.x >> 5, c = threadIdx.x & 31;
#pragma unroll
  for (int i = 0; i < 4; i++)
    tl[r8 + i * 8][c] = W[(size_t)(rt + r8 + i * 8) * C + ct + c];
  __syncthreads();
#pragma unroll
  for (int i = 0; i < 4; i++)
    Wt[(size_t)(ct + r8 + i * 8) * R + rt + c] = f2bf(tl[c][r8 + i * 8]);
}

// ------- W'^T[o][h*64+d] = sum_e P[h][d][e] * Wproj[h*64+e][o]  (bf16 out) -------
__global__ __launch_bounds__(256) void make_wproj(const float* __restrict__ proj,
                                                  const float* __restrict__ wproj,
                                                  unsigned short* __restrict__ WT) {
  int h = blockIdx.x, ot = blockIdx.y * 64;
  __shared__ float Pl[64][65];
  __shared__ float Wl[64][65];
  int t = threadIdx.x;
#pragma unroll
  for (int i = 0; i < 16; i++) {
    int idx = t + 256 * i;                  // 0..4095
    int a = idx >> 6, bc = idx & 63;
    Pl[a][bc] = proj[(size_t)h * 4096 + idx];
    Wl[a][bc] = wproj[(size_t)(h * 64 + a) * 1024 + ot + bc];
  }
  __syncthreads();
  int d = t & 63, ob = t >> 6;              // lanes vary d -> coalesced writes
#pragma unroll
  for (int i = 0; i < 16; i++) {
    int o = ob + i * 4;
    float acc = 0.f;
#pragma unroll
    for (int e = 0; e < 64; e++) acc += Pl[d][e] * Wl[e][o];
    WT[(size_t)(ot + o) * 1024 + h * 64 + d] = f2bf(acc);
  }
}

// ---------------- bf16 GEMM, Bt layout: C[M,N] = A[M,K] @ Bt[N,K]^T + bias ----------------
// Reg-staged, padded-72 LDS (conflict-free reads AND writes) — R2-proven form.
// EPI 0: split into q(*log2e/8)/k/v  [B,H,S,HD] bf16.  EPI 1: f32 out row-major.
template <int EPI>
__global__ __launch_bounds__(256) void gemm_bt(
    const unsigned short* __restrict__ A, const unsigned short* __restrict__ Bt,
    const float* __restrict__ bias, float* __restrict__ Cf,
    unsigned short* __restrict__ q, unsigned short* __restrict__ k,
    unsigned short* __restrict__ v, int M, int N, int K) {
  __shared__ unsigned short As[128][72];
  __shared__ unsigned short Bs[128][72];
  const int tid = threadIdx.x;
  const int m0 = blockIdx.y * 128, n0 = blockIdx.x * 128;
  f32x4 acc[4][4];
#pragma unroll
  for (int m = 0; m < 4; m++)
#pragma unroll
    for (int n = 0; n < 4; n++) acc[m][n] = f32x4{0.f, 0.f, 0.f, 0.f};
  const int w = tid >> 6, lane = tid & 63;
  const int wr = (w >> 1) * 64, wc = (w & 1) * 64;
  const int lrow = lane & 15, lk = (lane >> 4) * 8;

  for (int kt = 0; kt < K; kt += 64) {
    __syncthreads();
#pragma unroll
    for (int i = 0; i < 4; i++) {
      int cch = tid + 256 * i;              // 0..1023 chunks of 8 bf16
      int r = cch >> 3, c8 = cch & 7;
      *(u16x8*)(&As[r][c8 * 8]) = *(const u16x8*)(A + (size_t)(m0 + r) * K + kt + c8 * 8);
      *(u16x8*)(&Bs[r][c8 * 8]) = *(const u16x8*)(Bt + (size_t)(n0 + r) * K + kt + c8 * 8);
    }
    __syncthreads();
#pragma unroll
    for (int kk = 0; kk < 2; kk++) {
      bhalf8 af[4], bfr[4];
#pragma unroll
      for (int m = 0; m < 4; m++) af[m] = *(const bhalf8*)(&As[wr + m * 16 + lrow][kk * 32 + lk]);
#pragma unroll
      for (int n = 0; n < 4; n++) bfr[n] = *(const bhalf8*)(&Bs[wc + n * 16 + lrow][kk * 32 + lk]);
#pragma unroll
      for (int m = 0; m < 4; m++)
#pragma unroll
        for (int n = 0; n < 4; n++)
          acc[m][n] = __builtin_amdgcn_mfma_f32_16x16x32_bf16(af[m], bfr[n], acc[m][n], 0, 0, 0);
    }
  }
  // epilogue: D row = 4*(lane>>4)+r, col = lane&15 within each 16x16 frag
  const int g = lane >> 4, il = lane & 15;
#pragma unroll
  for (int m = 0; m < 4; m++) {
    int rowb = wr + m * 16 + 4 * g;
#pragma unroll
    for (int n = 0; n < 4; n++) {
      int col = n0 + wc + n * 16 + il;
      float bs = bias[col];
#pragma unroll
      for (int r = 0; r < 4; r++) {
        int row = m0 + rowb + r;
        float val = acc[m][n][r] + bs;
        if (EPI == 0) {
          int which = col >> 10, hh = (col >> 6) & 15, hd = col & 63;
          int b = row >> 11, s = row & 2047;
          size_t idx = ((size_t)(b * 16 + hh) * SDIM + s) * HDHD + hd;
          // q pre-scaled by 1/8 * log2(e) so attention can use native exp2
          unsigned short bv = f2bf(which == 0 ? val * 0.1803368801f : val);
          if (which == 0) q[idx] = bv;
          else if (which == 1) k[idx] = bv;
          else v[idx] = bv;
        } else {
          Cf[(size_t)row * N + col] = val;
        }
      }
    }
  }
}

// ---------------- causal flash attention, 128-row q blocks, KVBLK=64 ----------------
// Per wave: 32 q-rows (2 row-frags). K/V staged once per 128 q-rows -> staging and
// barrier count halve vs 64-row blocks. LDS strides 72 u16 (144 B) keep every b128
// access at 8 lanes per 4-bank group (conflict-free); u16x8 pairs in same dword merge.
__global__ __launch_bounds__(256, 4) void attn_kernel(const unsigned short* __restrict__ Q,
                                                      const unsigned short* __restrict__ Kb,
                                                      const unsigned short* __restrict__ Vb,
                                                      unsigned short* __restrict__ Om) {
  __shared__ unsigned short Ks[64][72];
  __shared__ unsigned short Vt[64][72];        // V transposed: Vt[d][k]
  __shared__ unsigned short Ps[4][32][72];     // per-wave P tile (32 q x 64 k)
  const int bh = blockIdx.x;                   // b*16+h
  const int qt = 15 - blockIdx.y;              // longest blocks dispatch first
  const int tid = threadIdx.x;
  const int w = tid >> 6, lane = tid & 63;
  const int g = lane >> 4, il = lane & 15;
  const int qbase = qt * 128 + w * 32;         // this wave's 32 q-rows
  const size_t bhS = (size_t)bh * SDIM;

  // Q fragments (q pre-scaled by log2e/8 in the QKV epilogue): 2 row-frags x 2 k-chunks
  bhalf8 qf[2][2];
#pragma unroll
  for (int f = 0; f < 2; f++) {
    const unsigned short* qp = Q + (bhS + qbase + f * 16 + il) * HDHD + g * 8;
    qf[f][0] = *(const bhalf8*)(qp);
    qf[f][1] = *(const bhalf8*)(qp + 32);
  }
  f32x4 oacc[2][4];
#pragma unroll
  for (int f = 0; f < 2; f++)
#pragma unroll
    for (int i = 0; i < 4; i++) oacc[f][i] = f32x4{0.f, 0.f, 0.f, 0.f};
  float mrun[2][4], lrun[2][4];
#pragma unroll
  for (int f = 0; f < 2; f++)
#pragma unroll
    for (int r = 0; r < 4; r++) { mrun[f][r] = -1e30f; lrun[f][r] = 0.f; }

  const int srow = tid >> 2;                   // K staging: row 0..63
  const int schk = (tid & 3) * 16;             // 16-u16 col chunk
  const int nt = 2 * qt + 2;                   // causal: KV tiles 0..2qt+1

  for (int kt = 0; kt < nt; kt++) {
    const size_t kbase = (bhS + (size_t)kt * 64) * HDHD;
    __syncthreads();
    // --- stage K rows (coalesced 32B/thread, conflict-free b128 LDS writes) ---
    {
      const unsigned short* src = Kb + kbase + srow * HDHD + schk;
      *(u16x8*)(&Ks[srow][schk]) = *(const u16x8*)(src);
      *(u16x8*)(&Ks[srow][schk + 8]) = *(const u16x8*)(src + 8);
    }
    // --- stage V transposed: lane=d gathers 16 k's (each load coalesced 128B/wave) ---
    {
      const unsigned short* vsrc = Vb + kbase + (size_t)(w * 16) * HDHD + lane;
      u16x8 va, vb2;
#pragma unroll
      for (int i = 0; i < 8; i++) va[i] = vsrc[i * HDHD];
#pragma unroll
      for (int i = 0; i < 8; i++) vb2[i] = vsrc[(8 + i) * HDHD];
      *(u16x8*)(&Vt[lane][w * 16]) = va;
      *(u16x8*)(&Vt[lane][w * 16 + 8]) = vb2;
    }
    __syncthreads();
    // --- S = Q @ K^T : 2 row-frags x 4 col-frags x 2 k-chunks = 16 MFMA ---
    f32x4 s[2][4];
#pragma unroll
    for (int f = 0; f < 2; f++)
#pragma unroll
      for (int c = 0; c < 4; c++) s[f][c] = f32x4{0.f, 0.f, 0.f, 0.f};
#pragma unroll
    for (int c = 0; c < 4; c++) {
      bhalf8 k0 = *(const bhalf8*)(&Ks[c * 16 + il][g * 8]);
      bhalf8 k1 = *(const bhalf8*)(&Ks[c * 16 + il][32 + g * 8]);
#pragma unroll
      for (int f = 0; f < 2; f++) {
        s[f][c] = __builtin_amdgcn_mfma_f32_16x16x32_bf16(qf[f][0], k0, s[f][c], 0, 0, 0);
        s[f][c] = __builtin_amdgcn_mfma_f32_16x16x32_bf16(qf[f][1], k1, s[f][c], 0, 0, 0);
      }
    }
    const bool diag = (kt >= 2 * qt);          // only last two tiles need masking
    const int kc0 = kt * 64 + il;
    // --- online softmax (wave-parallel, 16-lane groups), exp2-domain ---
#pragma unroll
    for (int f = 0; f < 2; f++) {
#pragma unroll
      for (int r = 0; r < 4; r++) {
        float v0 = s[f][0][r], v1 = s[f][1][r], v2 = s[f][2][r], v3 = s[f][3][r];
        if (diag) {
          int qr = qbase + f * 16 + 4 * g + r;
          if (kc0 > qr) v0 = -1e30f;
          if (kc0 + 16 > qr) v1 = -1e30f;
          if (kc0 + 32 > qr) v2 = -1e30f;
          if (kc0 + 48 > qr) v3 = -1e30f;
        }
        float mx = fmaxf(fmaxf(v0, v1), fmaxf(v2, v3));
        mx = fmaxf(mx, __shfl_xor(mx, 1));
        mx = fmaxf(mx, __shfl_xor(mx, 2));
        mx = fmaxf(mx, __shfl_xor(mx, 4));
        mx = fmaxf(mx, __shfl_xor(mx, 8));
        float mn = fmaxf(mrun[f][r], mx);
        float sc = exp2f(mrun[f][r] - mn);
        mrun[f][r] = mn;
        float p0 = exp2f(v0 - mn), p1 = exp2f(v1 - mn);
        float p2 = exp2f(v2 - mn), p3 = exp2f(v3 - mn);
        float rs = p0 + p1 + p2 + p3;
        rs += __shfl_xor(rs, 1);
        rs += __shfl_xor(rs, 2);
        rs += __shfl_xor(rs, 4);
        rs += __shfl_xor(rs, 8);
        lrun[f][r] = lrun[f][r] * sc + rs;
        int pr = f * 16 + 4 * g + r;
        Ps[w][pr][il] = f2bf(p0);
        Ps[w][pr][16 + il] = f2bf(p1);
        Ps[w][pr][32 + il] = f2bf(p2);
        Ps[w][pr][48 + il] = f2bf(p3);
#pragma unroll
        for (int df = 0; df < 4; df++) oacc[f][df][r] *= sc;
      }
    }
    // --- O += P @ V : 2 row-frags x 4 d-frags x 2 k-chunks = 16 MFMA ---
#pragma unroll
    for (int kk = 0; kk < 2; kk++) {
      bhalf8 pf0 = *(const bhalf8*)(&Ps[w][il][kk * 32 + g * 8]);
      bhalf8 pf1 = *(const bhalf8*)(&Ps[w][16 + il][kk * 32 + g * 8]);
#pragma unroll
      for (int df = 0; df < 4; df++) {
        bhalf8 vf = *(const bhalf8*)(&Vt[df * 16 + il][kk * 32 + g * 8]);
        oacc[0][df] = __builtin_amdgcn_mfma_f32_16x16x32_bf16(pf0, vf, oacc[0][df], 0, 0, 0);
        oacc[1][df] = __builtin_amdgcn_mfma_f32_16x16x32_bf16(pf1, vf, oacc[1][df], 0, 0, 0);
      }
    }
  }
  // --- epilogue: merged [B*S][D] bf16 ---
  const int b = bh >> 4, h = bh & 15;
#pragma unroll
  for (int f = 0; f < 2; f++) {
#pragma unroll
    for (int r = 0; r < 4; r++) {
      int srow2 = qbase + f * 16 + 4 * g + r;
      float inv = 1.f / lrun[f][r];
#pragma unroll
      for (int df = 0; df < 4; df++) {
        Om[((size_t)b * SDIM + srow2) * DDIM + h * HDHD + df * 16 + il] =
            f2bf(oacc[f][df][r] * inv);
      }
    }
  }
}

extern "C" void kernel_launch(void* const* d_in, const int* in_sizes, int n_in,
                              void* d_out, int out_size, void* d_ws, size_t ws_size,
                              hipStream_t stream) {
  const float* hidden = (const float*)d_in[0];
  const float* attn_w = (const float*)d_in[1];
  const float* attn_b = (const float*)d_in[2];
  const float* proj_w = (const float*)d_in[3];
  const float* proj_b = (const float*)d_in[4];
  const float* projectors = (const float*)d_in[5];
  float* out = (float*)d_out;
  char* ws = (char*)d_ws;
  (void)in_sizes; (void)n_in; (void)out_size; (void)ws_size;

  unsigned short* hseq   = (unsigned short*)(ws);               // [4096][1024] bf16  8 MB
  unsigned short* wqkvT  = (unsigned short*)(ws + 8388608);     // [3072][1024] bf16  6 MB
  unsigned short* qb     = (unsigned short*)(ws + 14680064);    // [B,H,S,HD] bf16    8 MB
  unsigned short* kb     = (unsigned short*)(ws + 23068672);    // 8 MB
  unsigned short* vb     = (unsigned short*)(ws + 31457280);    // 8 MB
  unsigned short* attnM  = (unsigned short*)(ws + 39845888);    // [4096][1024] bf16  8 MB
  unsigned short* wprojT = (unsigned short*)(ws + 48234496);    // [1024][1024] bf16  2 MB

  cvt_hidden<<<dim3(4096), dim3(256), 0, stream>>>(hidden, hseq);
  transpose_cvt<<<dim3(32, 96), dim3(256), 0, stream>>>(attn_w, wqkvT, 1024, 3072);
  make_wproj<<<dim3(16, 16), dim3(256), 0, stream>>>(projectors, proj_w, wprojT);
  gemm_bt<0><<<dim3(24, 32), dim3(256), 0, stream>>>(hseq, wqkvT, attn_b, nullptr,
                                                     qb, kb, vb, 4096, 3072, 1024);
  attn_kernel<<<dim3(32, 16), dim3(256), 0, stream>>>(qb, kb, vb, attnM);
  gemm_bt<1><<<dim3(8, 32), dim3(256), 0, stream>>>(attnM, wprojT, proj_b, out,
                                                    nullptr, nullptr, nullptr, 4096, 1024, 1024);
}

// Round 5
// 186.386 us; speedup vs baseline: 1.3373x; 1.3373x over previous
//
#include <hip/hip_runtime.h>

typedef __attribute__((ext_vector_type(8))) short bhalf8;   // 8 bf16 MFMA operand
typedef __attribute__((ext_vector_type(4))) float f32x4;
typedef __attribute__((ext_vector_type(8))) unsigned short u16x8;
typedef __attribute__((ext_vector_type(4))) unsigned short u16x4;

#define BDIM 2
#define SDIM 2048
#define DDIM 1024
#define HDIM 16
#define HDHD 64

__device__ __forceinline__ unsigned short f2bf(float f) {
  unsigned u = __builtin_bit_cast(unsigned, f);
  u += 0x7fffu + ((u >> 16) & 1u);           // RNE
  return (unsigned short)(u >> 16);
}
__device__ __forceinline__ float bf2f(unsigned short u) {
  return __builtin_bit_cast(float, (unsigned)u << 16);
}

// ---------------- elementwise f32 -> bf16 ----------------
__global__ __launch_bounds__(256) void cvt_hidden(const float* __restrict__ x,
                                                  unsigned short* __restrict__ y) {
  size_t i = ((size_t)blockIdx.x * 256 + threadIdx.x) * 4;
  f32x4 v = *(const f32x4*)(x + i);
  u16x4 o;
  o[0] = f2bf(v[0]); o[1] = f2bf(v[1]); o[2] = f2bf(v[2]); o[3] = f2bf(v[3]);
  *(u16x4*)(y + i) = o;
}

// ---------------- transpose + convert: W[R][C] f32 -> Wt[C][R] bf16 ----------------
__global__ __launch_bounds__(256) void transpose_cvt(const float* __restrict__ W,
                                                     unsigned short* __restrict__ Wt,
                                                     int R, int C) {
  __shared__ float tl[32][33];
  int rt = blockIdx.x * 32, ct = blockIdx.y * 32;
  int r8 = threadIdx.x >> 5, c = threadIdx.x & 31;
#pragma unroll
  for (int i = 0; i < 4; i++)
    tl[r8 + i * 8][c] = W[(size_t)(rt + r8 + i * 8) * C + ct + c];
  __syncthreads();
#pragma unroll
  for (int i = 0; i < 4; i++)
    Wt[(size_t)(ct + r8 + i * 8) * R + rt + c] = f2bf(tl[c][r8 + i * 8]);
}

// ------- W'^T[o][h*64+d] = sum_e P[h][d][e] * Wproj[h*64+e][o]  (bf16 out) -------
__global__ __launch_bounds__(256) void make_wproj(const float* __restrict__ proj,
                                                  const float* __restrict__ wproj,
                                                  unsigned short* __restrict__ WT) {
  int h = blockIdx.x, ot = blockIdx.y * 64;
  __shared__ float Pl[64][65];
  __shared__ float Wl[64][65];
  int t = threadIdx.x;
#pragma unroll
  for (int i = 0; i < 16; i++) {
    int idx = t + 256 * i;                  // 0..4095
    int a = idx >> 6, bc = idx & 63;
    Pl[a][bc] = proj[(size_t)h * 4096 + idx];
    Wl[a][bc] = wproj[(size_t)(h * 64 + a) * 1024 + ot + bc];
  }
  __syncthreads();
  int d = t & 63, ob = t >> 6;              // lanes vary d -> coalesced writes
#pragma unroll
  for (int i = 0; i < 16; i++) {
    int o = ob + i * 4;
    float acc = 0.f;
#pragma unroll
    for (int e = 0; e < 64; e++) acc += Pl[d][e] * Wl[e][o];
    WT[(size_t)(ot + o) * 1024 + h * 64 + d] = f2bf(acc);
  }
}

// ---------------- bf16 GEMM, Bt layout: C[M,N] = A[M,K] @ Bt[N,K]^T + bias ----------------
// Reg-staged, padded-72 LDS (conflict-free reads AND writes) — R2-proven form.
// EPI 0: split into q(*log2e/8)/k/v  [B,H,S,HD] bf16.  EPI 1: f32 out row-major.
template <int EPI>
__global__ __launch_bounds__(256) void gemm_bt(
    const unsigned short* __restrict__ A, const unsigned short* __restrict__ Bt,
    const float* __restrict__ bias, float* __restrict__ Cf,
    unsigned short* __restrict__ q, unsigned short* __restrict__ k,
    unsigned short* __restrict__ v, int M, int N, int K) {
  __shared__ unsigned short As[128][72];
  __shared__ unsigned short Bs[128][72];
  const int tid = threadIdx.x;
  const int m0 = blockIdx.y * 128, n0 = blockIdx.x * 128;
  f32x4 acc[4][4];
#pragma unroll
  for (int m = 0; m < 4; m++)
#pragma unroll
    for (int n = 0; n < 4; n++) acc[m][n] = f32x4{0.f, 0.f, 0.f, 0.f};
  const int w = tid >> 6, lane = tid & 63;
  const int wr = (w >> 1) * 64, wc = (w & 1) * 64;
  const int lrow = lane & 15, lk = (lane >> 4) * 8;

  for (int kt = 0; kt < K; kt += 64) {
    __syncthreads();
#pragma unroll
    for (int i = 0; i < 4; i++) {
      int cch = tid + 256 * i;              // 0..1023 chunks of 8 bf16
      int r = cch >> 3, c8 = cch & 7;
      *(u16x8*)(&As[r][c8 * 8]) = *(const u16x8*)(A + (size_t)(m0 + r) * K + kt + c8 * 8);
      *(u16x8*)(&Bs[r][c8 * 8]) = *(const u16x8*)(Bt + (size_t)(n0 + r) * K + kt + c8 * 8);
    }
    __syncthreads();
#pragma unroll
    for (int kk = 0; kk < 2; kk++) {
      bhalf8 af[4], bfr[4];
#pragma unroll
      for (int m = 0; m < 4; m++) af[m] = *(const bhalf8*)(&As[wr + m * 16 + lrow][kk * 32 + lk]);
#pragma unroll
      for (int n = 0; n < 4; n++) bfr[n] = *(const bhalf8*)(&Bs[wc + n * 16 + lrow][kk * 32 + lk]);
#pragma unroll
      for (int m = 0; m < 4; m++)
#pragma unroll
        for (int n = 0; n < 4; n++)
          acc[m][n] = __builtin_amdgcn_mfma_f32_16x16x32_bf16(af[m], bfr[n], acc[m][n], 0, 0, 0);
    }
  }
  // epilogue: D row = 4*(lane>>4)+r, col = lane&15 within each 16x16 frag
  const int g = lane >> 4, il = lane & 15;
#pragma unroll
  for (int m = 0; m < 4; m++) {
    int rowb = wr + m * 16 + 4 * g;
#pragma unroll
    for (int n = 0; n < 4; n++) {
      int col = n0 + wc + n * 16 + il;
      float bs = bias[col];
#pragma unroll
      for (int r = 0; r < 4; r++) {
        int row = m0 + rowb + r;
        float val = acc[m][n][r] + bs;
        if (EPI == 0) {
          int which = col >> 10, hh = (col >> 6) & 15, hd = col & 63;
          int b = row >> 11, s = row & 2047;
          size_t idx = ((size_t)(b * 16 + hh) * SDIM + s) * HDHD + hd;
          // q pre-scaled by 1/8 * log2(e) so attention can use native exp2
          unsigned short bv = f2bf(which == 0 ? val * 0.1803368801f : val);
          if (which == 0) q[idx] = bv;
          else if (which == 1) k[idx] = bv;
          else v[idx] = bv;
        } else {
          Cf[(size_t)row * N + col] = val;
        }
      }
    }
  }
}

// ============ split-KV causal flash attention ============
// Q tiles of 64 rows (32 of them). Each q-tile's KV range (qt+1 tiles of 64) is cut
// into segments of <=8 KV tiles. Block (bh, qt, seg) computes a partial:
//   PO[pidx][64][64] = O_seg / l_seg  (bf16),  ML[pidx][64] = (m_seg, l_seg)
// pidx = bh*80 + presum(qt) + seg, presum(qt) = 4a(a+1)+b(a+1), a=qt>>3, b=qt&7.
// attn_reduce combines <=4 segments: O = sum l_i 2^(m_i-M) Otilde_i / sum l_i 2^(m_i-M).
__global__ __launch_bounds__(256, 4) void attn_partial(const unsigned short* __restrict__ Q,
                                                       const unsigned short* __restrict__ Kb,
                                                       const unsigned short* __restrict__ Vb,
                                                       unsigned short* __restrict__ PO,
                                                       float2* __restrict__ ML) {
  const int bh = blockIdx.x;                   // b*16+h
  const int qt = 31 - blockIdx.y;              // longest q-tiles dispatch first
  const int seg = blockIdx.z;
  const int a = qt >> 3, bq = qt & 7;
  const int nseg = a + 1;                      // ceil((qt+1)/8)
  if (seg >= nseg) return;
  const int k0 = seg * 8;
  const int k1 = min(k0 + 8, qt + 1);

  __shared__ unsigned short Ks[64][72];
  __shared__ unsigned short Vt[64][72];        // V transposed: Vt[d][k]
  __shared__ unsigned short Ps[4][16][72];     // per-wave P tile (16 q x 64 k)
  const int tid = threadIdx.x;
  const int w = tid >> 6, lane = tid & 63;
  const int g = lane >> 4, il = lane & 15;
  const int qbase = qt * 64 + w * 16;
  const size_t bhS = (size_t)bh * SDIM;

  // Q fragments (pre-scaled by log2e/8 in the QKV epilogue)
  bhalf8 qf0, qf1;
  {
    const unsigned short* qp = Q + (bhS + qbase + il) * HDHD + g * 8;
    qf0 = *(const bhalf8*)(qp);
    qf1 = *(const bhalf8*)(qp + 32);
  }
  f32x4 oacc[4];
#pragma unroll
  for (int i = 0; i < 4; i++) oacc[i] = f32x4{0.f, 0.f, 0.f, 0.f};
  float mrun[4], lrun[4];
#pragma unroll
  for (int r = 0; r < 4; r++) { mrun[r] = -1e30f; lrun[r] = 0.f; }

  const int srow = tid >> 2;                   // K staging: row 0..63
  const int schk = (tid & 3) * 16;             // 16-u16 col chunk

  for (int kt = k0; kt < k1; kt++) {
    const size_t kbase = (bhS + (size_t)kt * 64) * HDHD;
    __syncthreads();
    {
      const unsigned short* src = Kb + kbase + srow * HDHD + schk;
      *(u16x8*)(&Ks[srow][schk]) = *(const u16x8*)(src);
      *(u16x8*)(&Ks[srow][schk + 8]) = *(const u16x8*)(src + 8);
    }
    {
      const unsigned short* vsrc = Vb + kbase + (size_t)(w * 16) * HDHD + lane;
      u16x8 va, vb2;
#pragma unroll
      for (int i = 0; i < 8; i++) va[i] = vsrc[i * HDHD];
#pragma unroll
      for (int i = 0; i < 8; i++) vb2[i] = vsrc[(8 + i) * HDHD];
      *(u16x8*)(&Vt[lane][w * 16]) = va;
      *(u16x8*)(&Vt[lane][w * 16 + 8]) = vb2;
    }
    __syncthreads();
    // --- S = Q @ K^T : 4 col-frags x 2 k-chunks = 8 MFMA ---
    f32x4 s[4];
#pragma unroll
    for (int c = 0; c < 4; c++) s[c] = f32x4{0.f, 0.f, 0.f, 0.f};
#pragma unroll
    for (int c = 0; c < 4; c++) {
      bhalf8 kf0 = *(const bhalf8*)(&Ks[c * 16 + il][g * 8]);
      bhalf8 kf1 = *(const bhalf8*)(&Ks[c * 16 + il][32 + g * 8]);
      s[c] = __builtin_amdgcn_mfma_f32_16x16x32_bf16(qf0, kf0, s[c], 0, 0, 0);
      s[c] = __builtin_amdgcn_mfma_f32_16x16x32_bf16(qf1, kf1, s[c], 0, 0, 0);
    }
    const bool diag = (kt == qt);
    const int kc0 = kt * 64 + il;
    // --- online softmax (wave-parallel, 16-lane groups), exp2-domain ---
#pragma unroll
    for (int r = 0; r < 4; r++) {
      float v0 = s[0][r], v1 = s[1][r], v2 = s[2][r], v3 = s[3][r];
      if (diag) {
        int qr = qbase + 4 * g + r;
        if (kc0 > qr) v0 = -1e30f;
        if (kc0 + 16 > qr) v1 = -1e30f;
        if (kc0 + 32 > qr) v2 = -1e30f;
        if (kc0 + 48 > qr) v3 = -1e30f;
      }
      float mx = fmaxf(fmaxf(v0, v1), fmaxf(v2, v3));
      mx = fmaxf(mx, __shfl_xor(mx, 1));
      mx = fmaxf(mx, __shfl_xor(mx, 2));
      mx = fmaxf(mx, __shfl_xor(mx, 4));
      mx = fmaxf(mx, __shfl_xor(mx, 8));
      float mn = fmaxf(mrun[r], mx);
      float sc = exp2f(mrun[r] - mn);
      mrun[r] = mn;
      float p0 = exp2f(v0 - mn), p1 = exp2f(v1 - mn);
      float p2 = exp2f(v2 - mn), p3 = exp2f(v3 - mn);
      float rs = p0 + p1 + p2 + p3;
      rs += __shfl_xor(rs, 1);
      rs += __shfl_xor(rs, 2);
      rs += __shfl_xor(rs, 4);
      rs += __shfl_xor(rs, 8);
      lrun[r] = lrun[r] * sc + rs;
      int pr = 4 * g + r;
      Ps[w][pr][il] = f2bf(p0);
      Ps[w][pr][16 + il] = f2bf(p1);
      Ps[w][pr][32 + il] = f2bf(p2);
      Ps[w][pr][48 + il] = f2bf(p3);
#pragma unroll
      for (int df = 0; df < 4; df++) oacc[df][r] *= sc;
    }
    // --- O += P @ V : 4 d-frags x 2 k-chunks = 8 MFMA ---
#pragma unroll
    for (int kk = 0; kk < 2; kk++) {
      bhalf8 pf = *(const bhalf8*)(&Ps[w][il][kk * 32 + g * 8]);
#pragma unroll
      for (int df = 0; df < 4; df++) {
        bhalf8 vf = *(const bhalf8*)(&Vt[df * 16 + il][kk * 32 + g * 8]);
        oacc[df] = __builtin_amdgcn_mfma_f32_16x16x32_bf16(pf, vf, oacc[df], 0, 0, 0);
      }
    }
  }
  // --- epilogue: normalized partial (bf16) + (m,l) ---
  const int pidx = bh * 80 + 4 * a * (a + 1) + bq * (a + 1) + seg;
#pragma unroll
  for (int r = 0; r < 4; r++) {
    int rl = w * 16 + 4 * g + r;               // local row 0..63
    float inv = 1.f / lrun[r];
#pragma unroll
    for (int df = 0; df < 4; df++)
      PO[(size_t)pidx * 4096 + rl * 64 + df * 16 + il] = f2bf(oacc[df][r] * inv);
    if (il == 0) ML[(size_t)pidx * 64 + rl] = make_float2(mrun[r], lrun[r]);
  }
}

// combine <=4 segments per (bh, q-tile); writes merged [B*S][D] bf16
__global__ __launch_bounds__(256) void attn_reduce(const unsigned short* __restrict__ PO,
                                                   const float2* __restrict__ ML,
                                                   unsigned short* __restrict__ Om) {
  const int bh = blockIdx.x, qt = blockIdx.y;
  const int a = qt >> 3, bq = qt & 7;
  const int nseg = a + 1;
  const int base = bh * 80 + 4 * a * (a + 1) + bq * (a + 1);
  const int t = threadIdx.x;
  const int r = t >> 2, dc = (t & 3) * 16;
  float2 mls[4];
  float M = -1e30f;
#pragma unroll
  for (int s = 0; s < 4; s++) {
    if (s < nseg) { mls[s] = ML[(size_t)(base + s) * 64 + r]; M = fmaxf(M, mls[s].x); }
  }
  float L = 0.f;
  float O[16];
#pragma unroll
  for (int j = 0; j < 16; j++) O[j] = 0.f;
#pragma unroll
  for (int s = 0; s < 4; s++) {
    if (s < nseg) {
      float wgt = mls[s].y * exp2f(mls[s].x - M);
      L += wgt;
      const unsigned short* p = PO + (size_t)(base + s) * 4096 + r * 64 + dc;
      u16x8 p0 = *(const u16x8*)p, p1 = *(const u16x8*)(p + 8);
#pragma unroll
      for (int j = 0; j < 8; j++) O[j] += wgt * bf2f(p0[j]);
#pragma unroll
      for (int j = 0; j < 8; j++) O[8 + j] += wgt * bf2f(p1[j]);
    }
  }
  float inv = 1.f / L;
  const int b = bh >> 4, h = bh & 15;
  size_t orow = ((size_t)b * SDIM + qt * 64 + r) * DDIM + h * HDHD + dc;
  u16x8 o0, o1;
#pragma unroll
  for (int j = 0; j < 8; j++) o0[j] = f2bf(O[j] * inv);
#pragma unroll
  for (int j = 0; j < 8; j++) o1[j] = f2bf(O[8 + j] * inv);
  *(u16x8*)(Om + orow) = o0;
  *(u16x8*)(Om + orow + 8) = o1;
}

// ---- fallback (small ws): R2 direct kernel, full KV range per q-tile ----
__global__ __launch_bounds__(256, 4) void attn_direct(const unsigned short* __restrict__ Q,
                                                      const unsigned short* __restrict__ Kb,
                                                      const unsigned short* __restrict__ Vb,
                                                      unsigned short* __restrict__ Om) {
  __shared__ unsigned short Ks[64][72];
  __shared__ unsigned short Vt[64][72];
  __shared__ unsigned short Ps[4][16][72];
  const int bh = blockIdx.x;
  const int qt = 31 - blockIdx.y;
  const int tid = threadIdx.x;
  const int w = tid >> 6, lane = tid & 63;
  const int g = lane >> 4, il = lane & 15;
  const int qbase = qt * 64 + w * 16;
  const size_t bhS = (size_t)bh * SDIM;
  bhalf8 qf0, qf1;
  {
    const unsigned short* qp = Q + (bhS + qbase + il) * HDHD + g * 8;
    qf0 = *(const bhalf8*)(qp);
    qf1 = *(const bhalf8*)(qp + 32);
  }
  f32x4 oacc[4];
#pragma unroll
  for (int i = 0; i < 4; i++) oacc[i] = f32x4{0.f, 0.f, 0.f, 0.f};
  float mrun[4], lrun[4];
#pragma unroll
  for (int r = 0; r < 4; r++) { mrun[r] = -1e30f; lrun[r] = 0.f; }
  const int srow = tid >> 2, schk = (tid & 3) * 16;
  const int nt = qt + 1;
  for (int kt = 0; kt < nt; kt++) {
    const size_t kbase = (bhS + (size_t)kt * 64) * HDHD;
    __syncthreads();
    {
      const unsigned short* src = Kb + kbase + srow * HDHD + schk;
      *(u16x8*)(&Ks[srow][schk]) = *(const u16x8*)(src);
      *(u16x8*)(&Ks[srow][schk + 8]) = *(const u16x8*)(src + 8);
    }
    {
      const unsigned short* vsrc = Vb + kbase + (size_t)(w * 16) * HDHD + lane;
      u16x8 va, vb2;
#pragma unroll
      for (int i = 0; i < 8; i++) va[i] = vsrc[i * HDHD];
#pragma unroll
      for (int i = 0; i < 8; i++) vb2[i] = vsrc[(8 + i) * HDHD];
      *(u16x8*)(&Vt[lane][w * 16]) = va;
      *(u16x8*)(&Vt[lane][w * 16 + 8]) = vb2;
    }
    __syncthreads();
    f32x4 s[4];
#pragma unroll
    for (int c = 0; c < 4; c++) s[c] = f32x4{0.f, 0.f, 0.f, 0.f};
#pragma unroll
    for (int c = 0; c < 4; c++) {
      bhalf8 kf0 = *(const bhalf8*)(&Ks[c * 16 + il][g * 8]);
      bhalf8 kf1 = *(const bhalf8*)(&Ks[c * 16 + il][32 + g * 8]);
      s[c] = __builtin_amdgcn_mfma_f32_16x16x32_bf16(qf0, kf0, s[c], 0, 0, 0);
      s[c] = __builtin_amdgcn_mfma_f32_16x16x32_bf16(qf1, kf1, s[c], 0, 0, 0);
    }
    const bool diag = (kt == qt);
    const int kc0 = kt * 64 + il;
#pragma unroll
    for (int r = 0; r < 4; r++) {
      float v0 = s[0][r], v1 = s[1][r], v2 = s[2][r], v3 = s[3][r];
      if (diag) {
        int qr = qbase + 4 * g + r;
        if (kc0 > qr) v0 = -1e30f;
        if (kc0 + 16 > qr) v1 = -1e30f;
        if (kc0 + 32 > qr) v2 = -1e30f;
        if (kc0 + 48 > qr) v3 = -1e30f;
      }
      float mx = fmaxf(fmaxf(v0, v1), fmaxf(v2, v3));
      mx = fmaxf(mx, __shfl_xor(mx, 1));
      mx = fmaxf(mx, __shfl_xor(mx, 2));
      mx = fmaxf(mx, __shfl_xor(mx, 4));
      mx = fmaxf(mx, __shfl_xor(mx, 8));
      float mn = fmaxf(mrun[r], mx);
      float sc = exp2f(mrun[r] - mn);
      mrun[r] = mn;
      float p0 = exp2f(v0 - mn), p1 = exp2f(v1 - mn);
      float p2 = exp2f(v2 - mn), p3 = exp2f(v3 - mn);
      float rs = p0 + p1 + p2 + p3;
      rs += __shfl_xor(rs, 1);
      rs += __shfl_xor(rs, 2);
      rs += __shfl_xor(rs, 4);
      rs += __shfl_xor(rs, 8);
      lrun[r] = lrun[r] * sc + rs;
      int pr = 4 * g + r;
      Ps[w][pr][il] = f2bf(p0);
      Ps[w][pr][16 + il] = f2bf(p1);
      Ps[w][pr][32 + il] = f2bf(p2);
      Ps[w][pr][48 + il] = f2bf(p3);
#pragma unroll
      for (int df = 0; df < 4; df++) oacc[df][r] *= sc;
    }
#pragma unroll
    for (int kk = 0; kk < 2; kk++) {
      bhalf8 pf = *(const bhalf8*)(&Ps[w][il][kk * 32 + g * 8]);
#pragma unroll
      for (int df = 0; df < 4; df++) {
        bhalf8 vf = *(const bhalf8*)(&Vt[df * 16 + il][kk * 32 + g * 8]);
        oacc[df] = __builtin_amdgcn_mfma_f32_16x16x32_bf16(pf, vf, oacc[df], 0, 0, 0);
      }
    }
  }
  const int b = bh >> 4, h = bh & 15;
#pragma unroll
  for (int r = 0; r < 4; r++) {
    int srow2 = qbase + 4 * g + r;
    float inv = 1.f / lrun[r];
#pragma unroll
    for (int df = 0; df < 4; df++) {
      Om[((size_t)b * SDIM + srow2) * DDIM + h * HDHD + df * 16 + il] =
          f2bf(oacc[df][r] * inv);
    }
  }
}

extern "C" void kernel_launch(void* const* d_in, const int* in_sizes, int n_in,
                              void* d_out, int out_size, void* d_ws, size_t ws_size,
                              hipStream_t stream) {
  const float* hidden = (const float*)d_in[0];
  const float* attn_w = (const float*)d_in[1];
  const float* attn_b = (const float*)d_in[2];
  const float* proj_w = (const float*)d_in[3];
  const float* proj_b = (const float*)d_in[4];
  const float* projectors = (const float*)d_in[5];
  float* out = (float*)d_out;
  char* ws = (char*)d_ws;
  (void)in_sizes; (void)n_in; (void)out_size;

  unsigned short* hseq   = (unsigned short*)(ws);               // [4096][1024] bf16  8 MB
  unsigned short* wqkvT  = (unsigned short*)(ws + 8388608);     // [3072][1024] bf16  6 MB
  unsigned short* qb     = (unsigned short*)(ws + 14680064);    // [B,H,S,HD] bf16    8 MB
  unsigned short* kb     = (unsigned short*)(ws + 23068672);    // 8 MB
  unsigned short* vb     = (unsigned short*)(ws + 31457280);    // 8 MB
  unsigned short* attnM  = (unsigned short*)(ws + 39845888);    // [4096][1024] bf16  8 MB
  unsigned short* wprojT = (unsigned short*)(ws + 48234496);    // [1024][1024] bf16  2 MB
  unsigned short* PO     = (unsigned short*)(ws + 50331648);    // 2560*4096 bf16    21 MB
  float2*         ML2    = (float2*)(ws + 71303168);            // 2560*64 float2   1.3 MB
  const size_t ws_needed = 71303168 + 1310720;                  // 72.6 MB

  cvt_hidden<<<dim3(4096), dim3(256), 0, stream>>>(hidden, hseq);
  transpose_cvt<<<dim3(32, 96), dim3(256), 0, stream>>>(attn_w, wqkvT, 1024, 3072);
  make_wproj<<<dim3(16, 16), dim3(256), 0, stream>>>(projectors, proj_w, wprojT);
  gemm_bt<0><<<dim3(24, 32), dim3(256), 0, stream>>>(hseq, wqkvT, attn_b, nullptr,
                                                     qb, kb, vb, 4096, 3072, 1024);
  if (ws_size >= ws_needed) {
    attn_partial<<<dim3(32, 32, 4), dim3(256), 0, stream>>>(qb, kb, vb, PO, ML2);
    attn_reduce<<<dim3(32, 32), dim3(256), 0, stream>>>(PO, ML2, attnM);
  } else {
    attn_direct<<<dim3(32, 32), dim3(256), 0, stream>>>(qb, kb, vb, attnM);
  }
  gemm_bt<1><<<dim3(8, 32), dim3(256), 0, stream>>>(attnM, wprojT, proj_b, out,
                                                    nullptr, nullptr, nullptr, 4096, 1024, 1024);
}

// Round 7
// 177.249 us; speedup vs baseline: 1.4062x; 1.0515x over previous
//
#include <hip/hip_runtime.h>

typedef __attribute__((ext_vector_type(8))) short bhalf8;   // 8 bf16 MFMA operand
typedef __attribute__((ext_vector_type(4))) float f32x4;
typedef __attribute__((ext_vector_type(8))) unsigned short u16x8;
typedef __attribute__((ext_vector_type(4))) unsigned short u16x4;

#define BDIM 2
#define SDIM 2048
#define DDIM 1024
#define HDIM 16
#define HDHD 64

__device__ __forceinline__ unsigned short f2bf(float f) {
  unsigned u = __builtin_bit_cast(unsigned, f);
  u += 0x7fffu + ((u >> 16) & 1u);           // RNE
  return (unsigned short)(u >> 16);
}

// ---------------- elementwise f32 -> bf16 ----------------
__global__ __launch_bounds__(256) void cvt_hidden(const float* __restrict__ x,
                                                  unsigned short* __restrict__ y) {
  size_t i = ((size_t)blockIdx.x * 256 + threadIdx.x) * 4;
  f32x4 v = *(const f32x4*)(x + i);
  u16x4 o;
  o[0] = f2bf(v[0]); o[1] = f2bf(v[1]); o[2] = f2bf(v[2]); o[3] = f2bf(v[3]);
  *(u16x4*)(y + i) = o;
}

// ---------------- transpose + convert: W[R][C] f32 -> Wt[C][R] bf16 ----------------
__global__ __launch_bounds__(256) void transpose_cvt(const float* __restrict__ W,
                                                     unsigned short* __restrict__ Wt,
                                                     int R, int C) {
  __shared__ float tl[32][33];
  int rt = blockIdx.x * 32, ct = blockIdx.y * 32;
  int r8 = threadIdx.x >> 5, c = threadIdx.x & 31;
#pragma unroll
  for (int i = 0; i < 4; i++)
    tl[r8 + i * 8][c] = W[(size_t)(rt + r8 + i * 8) * C + ct + c];
  __syncthreads();
#pragma unroll
  for (int i = 0; i < 4; i++)
    Wt[(size_t)(ct + r8 + i * 8) * R + rt + c] = f2bf(tl[c][r8 + i * 8]);
}

// ------- W'^T[o][h*64+d] = sum_e P[h][d][e] * Wproj[h*64+e][o]  (bf16 out) -------
__global__ __launch_bounds__(256) void make_wproj(const float* __restrict__ proj,
                                                  const float* __restrict__ wproj,
                                                  unsigned short* __restrict__ WT) {
  int h = blockIdx.x, ot = blockIdx.y * 64;
  __shared__ float Pl[64][65];
  __shared__ float Wl[64][65];
  int t = threadIdx.x;
#pragma unroll
  for (int i = 0; i < 16; i++) {
    int idx = t + 256 * i;                  // 0..4095
    int a = idx >> 6, bc = idx & 63;
    Pl[a][bc] = proj[(size_t)h * 4096 + idx];
    Wl[a][bc] = wproj[(size_t)(h * 64 + a) * 1024 + ot + bc];
  }
  __syncthreads();
  int d = t & 63, ob = t >> 6;              // lanes vary d -> coalesced writes
#pragma unroll
  for (int i = 0; i < 16; i++) {
    int o = ob + i * 4;
    float acc = 0.f;
#pragma unroll
    for (int e = 0; e < 64; e++) acc += Pl[d][e] * Wl[e][o];
    WT[(size_t)(ot + o) * 1024 + h * 64 + d] = f2bf(acc);
  }
}

// ---------------- bf16 GEMM, Bt layout: C[M,N] = A[M,K] @ Bt[N,K]^T + bias ----------------
// Reg-staged, padded-72 LDS (conflict-free reads AND writes) — R2-proven form.
// EPI 0: split into q(*log2e/8)/k/v  [B,H,S,HD] bf16.  EPI 1: f32 out row-major.
template <int EPI>
__global__ __launch_bounds__(256) void gemm_bt(
    const unsigned short* __restrict__ A, const unsigned short* __restrict__ Bt,
    const float* __restrict__ bias, float* __restrict__ Cf,
    unsigned short* __restrict__ q, unsigned short* __restrict__ k,
    unsigned short* __restrict__ v, int M, int N, int K) {
  __shared__ unsigned short As[128][72];
  __shared__ unsigned short Bs[128][72];
  const int tid = threadIdx.x;
  const int m0 = blockIdx.y * 128, n0 = blockIdx.x * 128;
  f32x4 acc[4][4];
#pragma unroll
  for (int m = 0; m < 4; m++)
#pragma unroll
    for (int n = 0; n < 4; n++) acc[m][n] = f32x4{0.f, 0.f, 0.f, 0.f};
  const int w = tid >> 6, lane = tid & 63;
  const int wr = (w >> 1) * 64, wc = (w & 1) * 64;
  const int lrow = lane & 15, lk = (lane >> 4) * 8;

  for (int kt = 0; kt < K; kt += 64) {
    __syncthreads();
#pragma unroll
    for (int i = 0; i < 4; i++) {
      int cch = tid + 256 * i;              // 0..1023 chunks of 8 bf16
      int r = cch >> 3, c8 = cch & 7;
      *(u16x8*)(&As[r][c8 * 8]) = *(const u16x8*)(A + (size_t)(m0 + r) * K + kt + c8 * 8);
      *(u16x8*)(&Bs[r][c8 * 8]) = *(const u16x8*)(Bt + (size_t)(n0 + r) * K + kt + c8 * 8);
    }
    __syncthreads();
#pragma unroll
    for (int kk = 0; kk < 2; kk++) {
      bhalf8 af[4], bfr[4];
#pragma unroll
      for (int m = 0; m < 4; m++) af[m] = *(const bhalf8*)(&As[wr + m * 16 + lrow][kk * 32 + lk]);
#pragma unroll
      for (int n = 0; n < 4; n++) bfr[n] = *(const bhalf8*)(&Bs[wc + n * 16 + lrow][kk * 32 + lk]);
#pragma unroll
      for (int m = 0; m < 4; m++)
#pragma unroll
        for (int n = 0; n < 4; n++)
          acc[m][n] = __builtin_amdgcn_mfma_f32_16x16x32_bf16(af[m], bfr[n], acc[m][n], 0, 0, 0);
    }
  }
  // epilogue: D row = 4*(lane>>4)+r, col = lane&15 within each 16x16 frag
  const int g = lane >> 4, il = lane & 15;
#pragma unroll
  for (int m = 0; m < 4; m++) {
    int rowb = wr + m * 16 + 4 * g;
#pragma unroll
    for (int n = 0; n < 4; n++) {
      int col = n0 + wc + n * 16 + il;
      float bs = bias[col];
#pragma unroll
      for (int r = 0; r < 4; r++) {
        int row = m0 + rowb + r;
        float val = acc[m][n][r] + bs;
        if (EPI == 0) {
          int which = col >> 10, hh = (col >> 6) & 15, hd = col & 63;
          int b = row >> 11, s = row & 2047;
          size_t idx = ((size_t)(b * 16 + hh) * SDIM + s) * HDHD + hd;
          // q pre-scaled by 1/8 * log2(e) so attention can use native exp2
          unsigned short bv = f2bf(which == 0 ? val * 0.1803368801f : val);
          if (which == 0) q[idx] = bv;
          else if (which == 1) k[idx] = bv;
          else v[idx] = bv;
        } else {
          Cf[(size_t)row * N + col] = val;
        }
      }
    }
  }
}

// ============ causal flash attention, swapped-operand layout ============
// 64-row q blocks, 2 waves x 32 q-rows, KVBLK=64.
// QK^T computed as S^T = mfma(K,Q): lane il owns q-row il of its frag-col, so the
// softmax row-reduce is per-lane + 2 shfl_xor (16,32). PV is also swapped
// (O^T = mfma(V^T, P)) so (m,l,rescale,normalize) all stay per-lane.
// P^T round-trips LDS as 4 packed b64 writes / 2 b128 reads per frag.
// All LDS strides 72 u16 (144 B) — proven conflict-minimal b128 pattern.
__global__ __launch_bounds__(128, 2) void attn_kernel(const unsigned short* __restrict__ Q,
                                                      const unsigned short* __restrict__ Kb,
                                                      const unsigned short* __restrict__ Vb,
                                                      unsigned short* __restrict__ Om) {
  __shared__ unsigned short Ks[64][72];        // K rows (also reused as O bounce)
  __shared__ unsigned short Vt[64][72];        // V transposed: Vt[d][k]
  __shared__ unsigned short Ps[2][32][72];     // per-wave P tile (32 q x 64 k)
  const int bh = blockIdx.x;                   // b*16+h
  const int qt = 31 - blockIdx.y;              // longest blocks dispatch first
  const int tid = threadIdx.x;                 // 0..127
  const int w = tid >> 6, lane = tid & 63;
  const int g = lane >> 4, il = lane & 15;
  const int qbase = qt * 64 + w * 32;          // this wave's 32 q-rows
  const size_t bhS = (size_t)bh * SDIM;

  // Q fragments (pre-scaled by log2e/8): 2 col-frags x 2 d-chunks
  bhalf8 qf[2][2];
#pragma unroll
  for (int f = 0; f < 2; f++) {
    const unsigned short* qp = Q + (bhS + qbase + f * 16 + il) * HDHD + g * 8;
    qf[f][0] = *(const bhalf8*)(qp);
    qf[f][1] = *(const bhalf8*)(qp + 32);
  }
  f32x4 oacc[2][4];                            // O^T[d=df*16+4g+r][q-col]
#pragma unroll
  for (int f = 0; f < 2; f++)
#pragma unroll
    for (int i = 0; i < 4; i++) oacc[f][i] = f32x4{0.f, 0.f, 0.f, 0.f};
  float mrun[2] = {-1e30f, -1e30f}, lrun[2] = {0.f, 0.f};

  // staging indices (128 threads)
  const int krow = tid >> 1;                   // K: row 0..63
  const int kchk = (tid & 1) * 32;             // 32-u16 half-row (this thread owns ALL 32)
  const int vd0 = (tid & 31) * 2;              // V: d pair
  const int vkg = (tid >> 5) * 16;             // V: k group of 16
  const int nt = qt + 1;

  for (int kt = 0; kt < nt; kt++) {
    const size_t kbase = (bhS + (size_t)kt * 64) * HDHD;
    __syncthreads();
    // --- stage K rows: 64 B per thread (full coverage: 2 thr x 32 u16 = 64 cols) ---
    {
      const unsigned short* src = Kb + kbase + krow * HDHD + kchk;
      *(u16x8*)(&Ks[krow][kchk]) = *(const u16x8*)(src);
      *(u16x8*)(&Ks[krow][kchk + 8]) = *(const u16x8*)(src + 8);
      *(u16x8*)(&Ks[krow][kchk + 16]) = *(const u16x8*)(src + 16);
      *(u16x8*)(&Ks[krow][kchk + 24]) = *(const u16x8*)(src + 24);
    }
    // --- stage V transposed: u32 loads carry a (d,d+1) pair; coalesced 128B/half-wave ---
    {
      const unsigned short* vsrc = Vb + kbase + (size_t)vkg * HDHD + vd0;
      u16x8 lo0, lo1, hi0, hi1;
#pragma unroll
      for (int i = 0; i < 8; i++) {
        unsigned vv = *(const unsigned*)(vsrc + i * HDHD);
        lo0[i] = (unsigned short)(vv & 0xffffu); hi0[i] = (unsigned short)(vv >> 16);
      }
#pragma unroll
      for (int i = 0; i < 8; i++) {
        unsigned vv = *(const unsigned*)(vsrc + (8 + i) * HDHD);
        lo1[i] = (unsigned short)(vv & 0xffffu); hi1[i] = (unsigned short)(vv >> 16);
      }
      *(u16x8*)(&Vt[vd0][vkg]) = lo0;     *(u16x8*)(&Vt[vd0][vkg + 8]) = lo1;
      *(u16x8*)(&Vt[vd0 + 1][vkg]) = hi0; *(u16x8*)(&Vt[vd0 + 1][vkg + 8]) = hi1;
    }
    __syncthreads();
    // --- S^T = mfma(K, Q): lane il holds S^T[k=c*16+4g+r][q=f*16+il] ---
    f32x4 s[2][4];
#pragma unroll
    for (int f = 0; f < 2; f++)
#pragma unroll
      for (int c = 0; c < 4; c++) s[f][c] = f32x4{0.f, 0.f, 0.f, 0.f};
#pragma unroll
    for (int c = 0; c < 4; c++) {
      bhalf8 kf0 = *(const bhalf8*)(&Ks[c * 16 + il][g * 8]);
      bhalf8 kf1 = *(const bhalf8*)(&Ks[c * 16 + il][32 + g * 8]);
#pragma unroll
      for (int f = 0; f < 2; f++) {
        s[f][c] = __builtin_amdgcn_mfma_f32_16x16x32_bf16(kf0, qf[f][0], s[f][c], 0, 0, 0);
        s[f][c] = __builtin_amdgcn_mfma_f32_16x16x32_bf16(kf1, qf[f][1], s[f][c], 0, 0, 0);
      }
    }
    const bool diag = (kt == qt);
    // --- per-lane online softmax (q = qbase + f*16 + il) ---
#pragma unroll
    for (int f = 0; f < 2; f++) {
      const int thr = w * 32 + f * 16 + il;    // local q row in block
      float p[4][4];
      float lmax = -1e30f;
#pragma unroll
      for (int c = 0; c < 4; c++)
#pragma unroll
        for (int r = 0; r < 4; r++) {
          float v = s[f][c][r];
          if (diag && (c * 16 + 4 * g + r > thr)) v = -1e30f;
          p[c][r] = v;
          lmax = fmaxf(lmax, v);
        }
      lmax = fmaxf(lmax, __shfl_xor(lmax, 16));
      lmax = fmaxf(lmax, __shfl_xor(lmax, 32));
      float mn = fmaxf(mrun[f], lmax);
      float sc = exp2f(mrun[f] - mn);
      mrun[f] = mn;
      float rs = 0.f;
#pragma unroll
      for (int c = 0; c < 4; c++)
#pragma unroll
        for (int r = 0; r < 4; r++) { p[c][r] = exp2f(p[c][r] - mn); rs += p[c][r]; }
      rs += __shfl_xor(rs, 16);
      rs += __shfl_xor(rs, 32);
      lrun[f] = lrun[f] * sc + rs;
#pragma unroll
      for (int df = 0; df < 4; df++)
#pragma unroll
        for (int r = 0; r < 4; r++) oacc[f][df][r] *= sc;
      // P store: 4 packed b64 writes (row q, cols k=c*16+4g..+3)
#pragma unroll
      for (int c = 0; c < 4; c++) {
        u16x4 pk;
#pragma unroll
        for (int r = 0; r < 4; r++) pk[r] = f2bf(p[c][r]);
        *(u16x4*)(&Ps[w][f * 16 + il][c * 16 + 4 * g]) = pk;
      }
    }
    // --- O^T += mfma(V^T, P): lane il accumulates O^T[d=df*16+4g+r][q=f*16+il] ---
#pragma unroll
    for (int kk = 0; kk < 2; kk++) {
      bhalf8 pf0 = *(const bhalf8*)(&Ps[w][il][kk * 32 + g * 8]);
      bhalf8 pf1 = *(const bhalf8*)(&Ps[w][16 + il][kk * 32 + g * 8]);
#pragma unroll
      for (int df = 0; df < 4; df++) {
        bhalf8 vf = *(const bhalf8*)(&Vt[df * 16 + il][kk * 32 + g * 8]);
        oacc[0][df] = __builtin_amdgcn_mfma_f32_16x16x32_bf16(vf, pf0, oacc[0][df], 0, 0, 0);
        oacc[1][df] = __builtin_amdgcn_mfma_f32_16x16x32_bf16(vf, pf1, oacc[1][df], 0, 0, 0);
      }
    }
  }
  // --- epilogue: transpose O^T through LDS (reuse Ks), coalesced global stores ---
  __syncthreads();
#pragma unroll
  for (int f = 0; f < 2; f++) {
    float inv = 1.f / lrun[f];
#pragma unroll
    for (int df = 0; df < 4; df++) {
      u16x4 o;
#pragma unroll
      for (int r = 0; r < 4; r++) o[r] = f2bf(oacc[f][df][r] * inv);
      *(u16x4*)(&Ks[w * 32 + f * 16 + il][df * 16 + 4 * g]) = o;
    }
  }
  __syncthreads();
  {
    const int row = tid >> 1, half = (tid & 1) * 32;
    const int b = bh >> 4, h = bh & 15;
    size_t obase = ((size_t)b * SDIM + qt * 64 + row) * DDIM + h * HDHD + half;
#pragma unroll
    for (int c8 = 0; c8 < 4; c8++)
      *(u16x8*)(Om + obase + c8 * 8) = *(const u16x8*)(&Ks[row][half + c8 * 8]);
  }
}

extern "C" void kernel_launch(void* const* d_in, const int* in_sizes, int n_in,
                              void* d_out, int out_size, void* d_ws, size_t ws_size,
                              hipStream_t stream) {
  const float* hidden = (const float*)d_in[0];
  const float* attn_w = (const float*)d_in[1];
  const float* attn_b = (const float*)d_in[2];
  const float* proj_w = (const float*)d_in[3];
  const float* proj_b = (const float*)d_in[4];
  const float* projectors = (const float*)d_in[5];
  float* out = (float*)d_out;
  char* ws = (char*)d_ws;
  (void)in_sizes; (void)n_in; (void)out_size; (void)ws_size;

  unsigned short* hseq   = (unsigned short*)(ws);               // [4096][1024] bf16  8 MB
  unsigned short* wqkvT  = (unsigned short*)(ws + 8388608);     // [3072][1024] bf16  6 MB
  unsigned short* qb     = (unsigned short*)(ws + 14680064);    // [B,H,S,HD] bf16    8 MB
  unsigned short* kb     = (unsigned short*)(ws + 23068672);    // 8 MB
  unsigned short* vb     = (unsigned short*)(ws + 31457280);    // 8 MB
  unsigned short* attnM  = (unsigned short*)(ws + 39845888);    // [4096][1024] bf16  8 MB
  unsigned short* wprojT = (unsigned short*)(ws + 48234496);    // [1024][1024] bf16  2 MB

  cvt_hidden<<<dim3(4096), dim3(256), 0, stream>>>(hidden, hseq);
  transpose_cvt<<<dim3(32, 96), dim3(256), 0, stream>>>(attn_w, wqkvT, 1024, 3072);
  make_wproj<<<dim3(16, 16), dim3(256), 0, stream>>>(projectors, proj_w, wprojT);
  gemm_bt<0><<<dim3(24, 32), dim3(256), 0, stream>>>(hseq, wqkvT, attn_b, nullptr,
                                                     qb, kb, vb, 4096, 3072, 1024);
  attn_kernel<<<dim3(32, 32), dim3(128), 0, stream>>>(qb, kb, vb, attnM);
  gemm_bt<1><<<dim3(8, 32), dim3(256), 0, stream>>>(attnM, wprojT, proj_b, out,
                                                    nullptr, nullptr, nullptr, 4096, 1024, 1024);
}

// Round 8
// 171.725 us; speedup vs baseline: 1.4515x; 1.0322x over previous
//
#include <hip/hip_runtime.h>

typedef __attribute__((ext_vector_type(8))) short bhalf8;   // 8 bf16 MFMA operand
typedef __attribute__((ext_vector_type(4))) float f32x4;
typedef __attribute__((ext_vector_type(8))) unsigned short u16x8;
typedef __attribute__((ext_vector_type(4))) unsigned short u16x4;

#define BDIM 2
#define SDIM 2048
#define DDIM 1024
#define HDIM 16
#define HDHD 64

__device__ __forceinline__ unsigned short f2bf(float f) {
  unsigned u = __builtin_bit_cast(unsigned, f);
  u += 0x7fffu + ((u >> 16) & 1u);           // RNE
  return (unsigned short)(u >> 16);
}
__device__ __forceinline__ float bf2f(unsigned short u) {
  return __builtin_bit_cast(float, (unsigned)u << 16);
}

// ---------------- elementwise f32 -> bf16 ----------------
__global__ __launch_bounds__(256) void cvt_hidden(const float* __restrict__ x,
                                                  unsigned short* __restrict__ y) {
  size_t i = ((size_t)blockIdx.x * 256 + threadIdx.x) * 4;
  f32x4 v = *(const f32x4*)(x + i);
  u16x4 o;
  o[0] = f2bf(v[0]); o[1] = f2bf(v[1]); o[2] = f2bf(v[2]); o[3] = f2bf(v[3]);
  *(u16x4*)(y + i) = o;
}

// ---------------- transpose + convert: W[R][C] f32 -> Wt[C][R] bf16 ----------------
__global__ __launch_bounds__(256) void transpose_cvt(const float* __restrict__ W,
                                                     unsigned short* __restrict__ Wt,
                                                     int R, int C) {
  __shared__ float tl[32][33];
  int rt = blockIdx.x * 32, ct = blockIdx.y * 32;
  int r8 = threadIdx.x >> 5, c = threadIdx.x & 31;
#pragma unroll
  for (int i = 0; i < 4; i++)
    tl[r8 + i * 8][c] = W[(size_t)(rt + r8 + i * 8) * C + ct + c];
  __syncthreads();
#pragma unroll
  for (int i = 0; i < 4; i++)
    Wt[(size_t)(ct + r8 + i * 8) * R + rt + c] = f2bf(tl[c][r8 + i * 8]);
}

// ------- W'^T[o][h*64+d] = sum_e P[h][d][e] * Wproj[h*64+e][o]  (bf16 out) -------
__global__ __launch_bounds__(256) void make_wproj(const float* __restrict__ proj,
                                                  const float* __restrict__ wproj,
                                                  unsigned short* __restrict__ WT) {
  int h = blockIdx.x, ot = blockIdx.y * 64;
  __shared__ float Pl[64][65];
  __shared__ float Wl[64][65];
  int t = threadIdx.x;
#pragma unroll
  for (int i = 0; i < 16; i++) {
    int idx = t + 256 * i;                  // 0..4095
    int a = idx >> 6, bc = idx & 63;
    Pl[a][bc] = proj[(size_t)h * 4096 + idx];
    Wl[a][bc] = wproj[(size_t)(h * 64 + a) * 1024 + ot + bc];
  }
  __syncthreads();
  int d = t & 63, ob = t >> 6;              // lanes vary d -> coalesced writes
#pragma unroll
  for (int i = 0; i < 16; i++) {
    int o = ob + i * 4;
    float acc = 0.f;
#pragma unroll
    for (int e = 0; e < 64; e++) acc += Pl[d][e] * Wl[e][o];
    WT[(size_t)(ot + o) * 1024 + h * 64 + d] = f2bf(acc);
  }
}

// ---------------- bf16 GEMM, Bt layout: C[M,N] = A[M,K] @ Bt[N,K]^T + bias ----------------
// Reg-staged, padded-72 LDS (conflict-free reads AND writes) — R2-proven form.
// EPI 0: split into q(*log2e/8)/k/v  [B,H,S,HD] bf16.  EPI 1: f32 out row-major.
template <int EPI>
__global__ __launch_bounds__(256) void gemm_bt(
    const unsigned short* __restrict__ A, const unsigned short* __restrict__ Bt,
    const float* __restrict__ bias, float* __restrict__ Cf,
    unsigned short* __restrict__ q, unsigned short* __restrict__ k,
    unsigned short* __restrict__ v, int M, int N, int K) {
  __shared__ unsigned short As[128][72];
  __shared__ unsigned short Bs[128][72];
  const int tid = threadIdx.x;
  const int m0 = blockIdx.y * 128, n0 = blockIdx.x * 128;
  f32x4 acc[4][4];
#pragma unroll
  for (int m = 0; m < 4; m++)
#pragma unroll
    for (int n = 0; n < 4; n++) acc[m][n] = f32x4{0.f, 0.f, 0.f, 0.f};
  const int w = tid >> 6, lane = tid & 63;
  const int wr = (w >> 1) * 64, wc = (w & 1) * 64;
  const int lrow = lane & 15, lk = (lane >> 4) * 8;

  for (int kt = 0; kt < K; kt += 64) {
    __syncthreads();
#pragma unroll
    for (int i = 0; i < 4; i++) {
      int cch = tid + 256 * i;              // 0..1023 chunks of 8 bf16
      int r = cch >> 3, c8 = cch & 7;
      *(u16x8*)(&As[r][c8 * 8]) = *(const u16x8*)(A + (size_t)(m0 + r) * K + kt + c8 * 8);
      *(u16x8*)(&Bs[r][c8 * 8]) = *(const u16x8*)(Bt + (size_t)(n0 + r) * K + kt + c8 * 8);
    }
    __syncthreads();
#pragma unroll
    for (int kk = 0; kk < 2; kk++) {
      bhalf8 af[4], bfr[4];
#pragma unroll
      for (int m = 0; m < 4; m++) af[m] = *(const bhalf8*)(&As[wr + m * 16 + lrow][kk * 32 + lk]);
#pragma unroll
      for (int n = 0; n < 4; n++) bfr[n] = *(const bhalf8*)(&Bs[wc + n * 16 + lrow][kk * 32 + lk]);
#pragma unroll
      for (int m = 0; m < 4; m++)
#pragma unroll
        for (int n = 0; n < 4; n++)
          acc[m][n] = __builtin_amdgcn_mfma_f32_16x16x32_bf16(af[m], bfr[n], acc[m][n], 0, 0, 0);
    }
  }
  // epilogue: D row = 4*(lane>>4)+r, col = lane&15 within each 16x16 frag
  const int g = lane >> 4, il = lane & 15;
#pragma unroll
  for (int m = 0; m < 4; m++) {
    int rowb = wr + m * 16 + 4 * g;
#pragma unroll
    for (int n = 0; n < 4; n++) {
      int col = n0 + wc + n * 16 + il;
      float bs = bias[col];
#pragma unroll
      for (int r = 0; r < 4; r++) {
        int row = m0 + rowb + r;
        float val = acc[m][n][r] + bs;
        if (EPI == 0) {
          int which = col >> 10, hh = (col >> 6) & 15, hd = col & 63;
          int b = row >> 11, s = row & 2047;
          size_t idx = ((size_t)(b * 16 + hh) * SDIM + s) * HDHD + hd;
          // q pre-scaled by 1/8 * log2(e) so attention can use native exp2
          unsigned short bv = f2bf(which == 0 ? val * 0.1803368801f : val);
          if (which == 0) q[idx] = bv;
          else if (which == 1) k[idx] = bv;
          else v[idx] = bv;
        } else {
          Cf[(size_t)row * N + col] = val;
        }
      }
    }
  }
}

// ============ split-KV causal flash attention, swapped-operand layout ============
// 64-row q tiles, 2 waves x 32 q-rows, KVBLK=64, segments of <=8 KV tiles.
// S^T = mfma(K,Q) -> per-lane softmax state; O^T = mfma(V^T,P).
// Register prefetch: tile t+1's K/V global loads issue right after staging tile t,
// landing during tile t's MFMA+softmax (T14). Wave-uniform defer-max (T13, THR=7).
__global__ __launch_bounds__(128, 3) void attn_partial(const unsigned short* __restrict__ Q,
                                                       const unsigned short* __restrict__ Kb,
                                                       const unsigned short* __restrict__ Vb,
                                                       unsigned short* __restrict__ PO,
                                                       float2* __restrict__ ML) {
  __shared__ unsigned short Ks[64][72];        // K rows (also reused as O bounce)
  __shared__ unsigned short Vt[64][72];        // V transposed: Vt[d][k]
  __shared__ unsigned short Ps[2][32][72];     // per-wave P tile (32 q x 64 k)
  const int bh = blockIdx.x;                   // b*16+h
  const int qt = 31 - blockIdx.y;              // longest q-tiles dispatch first
  const int seg = blockIdx.z;
  const int a = qt >> 3, bq = qt & 7;
  const int nseg = a + 1;                      // ceil((qt+1)/8)
  if (seg >= nseg) return;
  const int k0 = seg * 8;
  const int k1 = min(k0 + 8, qt + 1);

  const int tid = threadIdx.x;                 // 0..127
  const int w = tid >> 6, lane = tid & 63;
  const int g = lane >> 4, il = lane & 15;
  const int qbase = qt * 64 + w * 32;          // this wave's 32 q-rows
  const size_t bhS = (size_t)bh * SDIM;

  // Q fragments (pre-scaled by log2e/8): 2 col-frags x 2 d-chunks
  bhalf8 qf[2][2];
#pragma unroll
  for (int f = 0; f < 2; f++) {
    const unsigned short* qp = Q + (bhS + qbase + f * 16 + il) * HDHD + g * 8;
    qf[f][0] = *(const bhalf8*)(qp);
    qf[f][1] = *(const bhalf8*)(qp + 32);
  }
  f32x4 oacc[2][4];                            // O^T[d=df*16+4g+r][q-col]
#pragma unroll
  for (int f = 0; f < 2; f++)
#pragma unroll
    for (int i = 0; i < 4; i++) oacc[f][i] = f32x4{0.f, 0.f, 0.f, 0.f};
  float mrun[2] = {-1e30f, -1e30f}, lrun[2] = {0.f, 0.f};

  // staging indices (128 threads)
  const int krow = tid >> 1;                   // K: row 0..63
  const int kchk = (tid & 1) * 32;             // 32-u16 half-row
  const int vd0 = (tid & 31) * 2;              // V: d pair
  const int vkg = (tid >> 5) * 16;             // V: k group of 16

  // ---- prefetch registers: tile k0 ----
  u16x8 kr[4];
  unsigned vr[16];
  {
    const size_t kb0 = (bhS + (size_t)k0 * 64) * HDHD;
    const unsigned short* ksrc = Kb + kb0 + krow * HDHD + kchk;
#pragma unroll
    for (int i = 0; i < 4; i++) kr[i] = *(const u16x8*)(ksrc + i * 8);
    const unsigned short* vsrc = Vb + kb0 + (size_t)vkg * HDHD + vd0;
#pragma unroll
    for (int i = 0; i < 16; i++) vr[i] = *(const unsigned*)(vsrc + i * HDHD);
  }

  for (int kt = k0; kt < k1; kt++) {
    __syncthreads();
    // --- stage current tile from regs into LDS ---
#pragma unroll
    for (int i = 0; i < 4; i++) *(u16x8*)(&Ks[krow][kchk + i * 8]) = kr[i];
    {
      u16x8 lo0, lo1, hi0, hi1;
#pragma unroll
      for (int i = 0; i < 8; i++) {
        lo0[i] = (unsigned short)(vr[i] & 0xffffu); hi0[i] = (unsigned short)(vr[i] >> 16);
      }
#pragma unroll
      for (int i = 0; i < 8; i++) {
        lo1[i] = (unsigned short)(vr[8 + i] & 0xffffu); hi1[i] = (unsigned short)(vr[8 + i] >> 16);
      }
      *(u16x8*)(&Vt[vd0][vkg]) = lo0;     *(u16x8*)(&Vt[vd0][vkg + 8]) = lo1;
      *(u16x8*)(&Vt[vd0 + 1][vkg]) = hi0; *(u16x8*)(&Vt[vd0 + 1][vkg + 8]) = hi1;
    }
    // --- issue next-tile loads (land during this tile's compute) ---
    if (kt + 1 < k1) {
      const size_t kbn = (bhS + (size_t)(kt + 1) * 64) * HDHD;
      const unsigned short* ksrc = Kb + kbn + krow * HDHD + kchk;
#pragma unroll
      for (int i = 0; i < 4; i++) kr[i] = *(const u16x8*)(ksrc + i * 8);
      const unsigned short* vsrc = Vb + kbn + (size_t)vkg * HDHD + vd0;
#pragma unroll
      for (int i = 0; i < 16; i++) vr[i] = *(const unsigned*)(vsrc + i * HDHD);
    }
    __syncthreads();
    // --- S^T = mfma(K, Q): lane il holds S^T[k=c*16+4g+r][q=f*16+il] ---
    f32x4 s[2][4];
#pragma unroll
    for (int f = 0; f < 2; f++)
#pragma unroll
      for (int c = 0; c < 4; c++) s[f][c] = f32x4{0.f, 0.f, 0.f, 0.f};
#pragma unroll
    for (int c = 0; c < 4; c++) {
      bhalf8 kf0 = *(const bhalf8*)(&Ks[c * 16 + il][g * 8]);
      bhalf8 kf1 = *(const bhalf8*)(&Ks[c * 16 + il][32 + g * 8]);
#pragma unroll
      for (int f = 0; f < 2; f++) {
        s[f][c] = __builtin_amdgcn_mfma_f32_16x16x32_bf16(kf0, qf[f][0], s[f][c], 0, 0, 0);
        s[f][c] = __builtin_amdgcn_mfma_f32_16x16x32_bf16(kf1, qf[f][1], s[f][c], 0, 0, 0);
      }
    }
    const bool diag = (kt == qt);
    // --- per-lane online softmax, wave-uniform defer-max (THR=7) ---
    float lmax[2];
#pragma unroll
    for (int f = 0; f < 2; f++) {
      const int thr = w * 32 + f * 16 + il;    // local q row in block
      float lm = -1e30f;
#pragma unroll
      for (int c = 0; c < 4; c++)
#pragma unroll
        for (int r = 0; r < 4; r++) {
          float v = s[f][c][r];
          if (diag && (c * 16 + 4 * g + r > thr)) v = -1e30f;
          s[f][c][r] = v;
          lm = fmaxf(lm, v);
        }
      lm = fmaxf(lm, __shfl_xor(lm, 16));
      lm = fmaxf(lm, __shfl_xor(lm, 32));
      lmax[f] = lm;
    }
    if (!__all((lmax[0] <= mrun[0] + 7.f) && (lmax[1] <= mrun[1] + 7.f))) {
#pragma unroll
      for (int f = 0; f < 2; f++) {
        float mn = fmaxf(mrun[f], lmax[f]);
        float sc = exp2f(mrun[f] - mn);
        mrun[f] = mn;
        lrun[f] *= sc;
#pragma unroll
        for (int df = 0; df < 4; df++)
#pragma unroll
          for (int r = 0; r < 4; r++) oacc[f][df][r] *= sc;
      }
    }
#pragma unroll
    for (int f = 0; f < 2; f++) {
      float rs = 0.f;
#pragma unroll
      for (int c = 0; c < 4; c++) {
        u16x4 pk;
#pragma unroll
        for (int r = 0; r < 4; r++) {
          float pv = exp2f(s[f][c][r] - mrun[f]);
          rs += pv;
          pk[r] = f2bf(pv);
        }
        *(u16x4*)(&Ps[w][f * 16 + il][c * 16 + 4 * g]) = pk;
      }
      rs += __shfl_xor(rs, 16);
      rs += __shfl_xor(rs, 32);
      lrun[f] += rs;
    }
    // --- O^T += mfma(V^T, P) ---
#pragma unroll
    for (int kk = 0; kk < 2; kk++) {
      bhalf8 pf0 = *(const bhalf8*)(&Ps[w][il][kk * 32 + g * 8]);
      bhalf8 pf1 = *(const bhalf8*)(&Ps[w][16 + il][kk * 32 + g * 8]);
#pragma unroll
      for (int df = 0; df < 4; df++) {
        bhalf8 vf = *(const bhalf8*)(&Vt[df * 16 + il][kk * 32 + g * 8]);
        oacc[0][df] = __builtin_amdgcn_mfma_f32_16x16x32_bf16(vf, pf0, oacc[0][df], 0, 0, 0);
        oacc[1][df] = __builtin_amdgcn_mfma_f32_16x16x32_bf16(vf, pf1, oacc[1][df], 0, 0, 0);
      }
    }
  }
  // --- epilogue: normalized partial O (via LDS transpose) + (m,l) ---
  const int pidx = bh * 80 + 4 * a * (a + 1) + bq * (a + 1) + seg;
  __syncthreads();
#pragma unroll
  for (int f = 0; f < 2; f++) {
    float inv = 1.f / lrun[f];
#pragma unroll
    for (int df = 0; df < 4; df++) {
      u16x4 o;
#pragma unroll
      for (int r = 0; r < 4; r++) o[r] = f2bf(oacc[f][df][r] * inv);
      *(u16x4*)(&Ks[w * 32 + f * 16 + il][df * 16 + 4 * g]) = o;
    }
  }
  if (g == 0) {
#pragma unroll
    for (int f = 0; f < 2; f++)
      ML[(size_t)pidx * 64 + w * 32 + f * 16 + il] = make_float2(mrun[f], lrun[f]);
  }
  __syncthreads();
  {
    const int row = tid >> 1, half = (tid & 1) * 32;
    unsigned short* dst = PO + (size_t)pidx * 4096 + (size_t)row * 64 + half;
#pragma unroll
    for (int c8 = 0; c8 < 4; c8++)
      *(u16x8*)(dst + c8 * 8) = *(const u16x8*)(&Ks[row][half + c8 * 8]);
  }
}

// combine <=4 segments per (bh, q-tile); writes merged [B*S][D] bf16
__global__ __launch_bounds__(256) void attn_reduce(const unsigned short* __restrict__ PO,
                                                   const float2* __restrict__ ML,
                                                   unsigned short* __restrict__ Om) {
  const int bh = blockIdx.x, qt = blockIdx.y;
  const int a = qt >> 3, bq = qt & 7;
  const int nseg = a + 1;
  const int base = bh * 80 + 4 * a * (a + 1) + bq * (a + 1);
  const int t = threadIdx.x;
  const int r = t >> 2, dc = (t & 3) * 16;
  float2 mls[4];
  float M = -1e30f;
#pragma unroll
  for (int s = 0; s < 4; s++) {
    if (s < nseg) { mls[s] = ML[(size_t)(base + s) * 64 + r]; M = fmaxf(M, mls[s].x); }
  }
  float L = 0.f;
  float O[16];
#pragma unroll
  for (int j = 0; j < 16; j++) O[j] = 0.f;
#pragma unroll
  for (int s = 0; s < 4; s++) {
    if (s < nseg) {
      float wgt = mls[s].y * exp2f(mls[s].x - M);
      L += wgt;
      const unsigned short* p = PO + (size_t)(base + s) * 4096 + r * 64 + dc;
      u16x8 p0 = *(const u16x8*)p, p1 = *(const u16x8*)(p + 8);
#pragma unroll
      for (int j = 0; j < 8; j++) O[j] += wgt * bf2f(p0[j]);
#pragma unroll
      for (int j = 0; j < 8; j++) O[8 + j] += wgt * bf2f(p1[j]);
    }
  }
  float inv = 1.f / L;
  const int b = bh >> 4, h = bh & 15;
  size_t orow = ((size_t)b * SDIM + qt * 64 + r) * DDIM + h * HDHD + dc;
  u16x8 o0, o1;
#pragma unroll
  for (int j = 0; j < 8; j++) o0[j] = f2bf(O[j] * inv);
#pragma unroll
  for (int j = 0; j < 8; j++) o1[j] = f2bf(O[8 + j] * inv);
  *(u16x8*)(Om + orow) = o0;
  *(u16x8*)(Om + orow + 8) = o1;
}

// ---- fallback (small ws): R7 direct swapped kernel, full KV range per q-tile ----
__global__ __launch_bounds__(128, 2) void attn_direct(const unsigned short* __restrict__ Q,
                                                      const unsigned short* __restrict__ Kb,
                                                      const unsigned short* __restrict__ Vb,
                                                      unsigned short* __restrict__ Om) {
  __shared__ unsigned short Ks[64][72];
  __shared__ unsigned short Vt[64][72];
  __shared__ unsigned short Ps[2][32][72];
  const int bh = blockIdx.x;
  const int qt = 31 - blockIdx.y;
  const int tid = threadIdx.x;
  const int w = tid >> 6, lane = tid & 63;
  const int g = lane >> 4, il = lane & 15;
  const int qbase = qt * 64 + w * 32;
  const size_t bhS = (size_t)bh * SDIM;
  bhalf8 qf[2][2];
#pragma unroll
  for (int f = 0; f < 2; f++) {
    const unsigned short* qp = Q + (bhS + qbase + f * 16 + il) * HDHD + g * 8;
    qf[f][0] = *(const bhalf8*)(qp);
    qf[f][1] = *(const bhalf8*)(qp + 32);
  }
  f32x4 oacc[2][4];
#pragma unroll
  for (int f = 0; f < 2; f++)
#pragma unroll
    for (int i = 0; i < 4; i++) oacc[f][i] = f32x4{0.f, 0.f, 0.f, 0.f};
  float mrun[2] = {-1e30f, -1e30f}, lrun[2] = {0.f, 0.f};
  const int krow = tid >> 1, kchk = (tid & 1) * 32;
  const int vd0 = (tid & 31) * 2, vkg = (tid >> 5) * 16;
  const int nt = qt + 1;
  for (int kt = 0; kt < nt; kt++) {
    const size_t kbase = (bhS + (size_t)kt * 64) * HDHD;
    __syncthreads();
    {
      const unsigned short* src = Kb + kbase + krow * HDHD + kchk;
#pragma unroll
      for (int i = 0; i < 4; i++) *(u16x8*)(&Ks[krow][kchk + i * 8]) = *(const u16x8*)(src + i * 8);
    }
    {
      const unsigned short* vsrc = Vb + kbase + (size_t)vkg * HDHD + vd0;
      u16x8 lo0, lo1, hi0, hi1;
#pragma unroll
      for (int i = 0; i < 8; i++) {
        unsigned vv = *(const unsigned*)(vsrc + i * HDHD);
        lo0[i] = (unsigned short)(vv & 0xffffu); hi0[i] = (unsigned short)(vv >> 16);
      }
#pragma unroll
      for (int i = 0; i < 8; i++) {
        unsigned vv = *(const unsigned*)(vsrc + (8 + i) * HDHD);
        lo1[i] = (unsigned short)(vv & 0xffffu); hi1[i] = (unsigned short)(vv >> 16);
      }
      *(u16x8*)(&Vt[vd0][vkg]) = lo0;     *(u16x8*)(&Vt[vd0][vkg + 8]) = lo1;
      *(u16x8*)(&Vt[vd0 + 1][vkg]) = hi0; *(u16x8*)(&Vt[vd0 + 1][vkg + 8]) = hi1;
    }
    __syncthreads();
    f32x4 s[2][4];
#pragma unroll
    for (int f = 0; f < 2; f++)
#pragma unroll
      for (int c = 0; c < 4; c++) s[f][c] = f32x4{0.f, 0.f, 0.f, 0.f};
#pragma unroll
    for (int c = 0; c < 4; c++) {
      bhalf8 kf0 = *(const bhalf8*)(&Ks[c * 16 + il][g * 8]);
      bhalf8 kf1 = *(const bhalf8*)(&Ks[c * 16 + il][32 + g * 8]);
#pragma unroll
      for (int f = 0; f < 2; f++) {
        s[f][c] = __builtin_amdgcn_mfma_f32_16x16x32_bf16(kf0, qf[f][0], s[f][c], 0, 0, 0);
        s[f][c] = __builtin_amdgcn_mfma_f32_16x16x32_bf16(kf1, qf[f][1], s[f][c], 0, 0, 0);
      }
    }
    const bool diag = (kt == qt);
#pragma unroll
    for (int f = 0; f < 2; f++) {
      const int thr = w * 32 + f * 16 + il;
      float p[4][4];
      float lmax = -1e30f;
#pragma unroll
      for (int c = 0; c < 4; c++)
#pragma unroll
        for (int r = 0; r < 4; r++) {
          float v = s[f][c][r];
          if (diag && (c * 16 + 4 * g + r > thr)) v = -1e30f;
          p[c][r] = v;
          lmax = fmaxf(lmax, v);
        }
      lmax = fmaxf(lmax, __shfl_xor(lmax, 16));
      lmax = fmaxf(lmax, __shfl_xor(lmax, 32));
      float mn = fmaxf(mrun[f], lmax);
      float sc = exp2f(mrun[f] - mn);
      mrun[f] = mn;
      float rs = 0.f;
#pragma unroll
      for (int c = 0; c < 4; c++)
#pragma unroll
        for (int r = 0; r < 4; r++) { p[c][r] = exp2f(p[c][r] - mn); rs += p[c][r]; }
      rs += __shfl_xor(rs, 16);
      rs += __shfl_xor(rs, 32);
      lrun[f] = lrun[f] * sc + rs;
#pragma unroll
      for (int df = 0; df < 4; df++)
#pragma unroll
        for (int r = 0; r < 4; r++) oacc[f][df][r] *= sc;
#pragma unroll
      for (int c = 0; c < 4; c++) {
        u16x4 pk;
#pragma unroll
        for (int r = 0; r < 4; r++) pk[r] = f2bf(p[c][r]);
        *(u16x4*)(&Ps[w][f * 16 + il][c * 16 + 4 * g]) = pk;
      }
    }
#pragma unroll
    for (int kk = 0; kk < 2; kk++) {
      bhalf8 pf0 = *(const bhalf8*)(&Ps[w][il][kk * 32 + g * 8]);
      bhalf8 pf1 = *(const bhalf8*)(&Ps[w][16 + il][kk * 32 + g * 8]);
#pragma unroll
      for (int df = 0; df < 4; df++) {
        bhalf8 vf = *(const bhalf8*)(&Vt[df * 16 + il][kk * 32 + g * 8]);
        oacc[0][df] = __builtin_amdgcn_mfma_f32_16x16x32_bf16(vf, pf0, oacc[0][df], 0, 0, 0);
        oacc[1][df] = __builtin_amdgcn_mfma_f32_16x16x32_bf16(vf, pf1, oacc[1][df], 0, 0, 0);
      }
    }
  }
  __syncthreads();
#pragma unroll
  for (int f = 0; f < 2; f++) {
    float inv = 1.f / lrun[f];
#pragma unroll
    for (int df = 0; df < 4; df++) {
      u16x4 o;
#pragma unroll
      for (int r = 0; r < 4; r++) o[r] = f2bf(oacc[f][df][r] * inv);
      *(u16x4*)(&Ks[w * 32 + f * 16 + il][df * 16 + 4 * g]) = o;
    }
  }
  __syncthreads();
  {
    const int row = tid >> 1, half = (tid & 1) * 32;
    const int b = bh >> 4, h = bh & 15;
    size_t obase = ((size_t)b * SDIM + qt * 64 + row) * DDIM + h * HDHD + half;
#pragma unroll
    for (int c8 = 0; c8 < 4; c8++)
      *(u16x8*)(Om + obase + c8 * 8) = *(const u16x8*)(&Ks[row][half + c8 * 8]);
  }
}

extern "C" void kernel_launch(void* const* d_in, const int* in_sizes, int n_in,
                              void* d_out, int out_size, void* d_ws, size_t ws_size,
                              hipStream_t stream) {
  const float* hidden = (const float*)d_in[0];
  const float* attn_w = (const float*)d_in[1];
  const float* attn_b = (const float*)d_in[2];
  const float* proj_w = (const float*)d_in[3];
  const float* proj_b = (const float*)d_in[4];
  const float* projectors = (const float*)d_in[5];
  float* out = (float*)d_out;
  char* ws = (char*)d_ws;
  (void)in_sizes; (void)n_in; (void)out_size;

  unsigned short* hseq   = (unsigned short*)(ws);               // [4096][1024] bf16  8 MB
  unsigned short* wqkvT  = (unsigned short*)(ws + 8388608);     // [3072][1024] bf16  6 MB
  unsigned short* qb     = (unsigned short*)(ws + 14680064);    // [B,H,S,HD] bf16    8 MB
  unsigned short* kb     = (unsigned short*)(ws + 23068672);    // 8 MB
  unsigned short* vb     = (unsigned short*)(ws + 31457280);    // 8 MB
  unsigned short* attnM  = (unsigned short*)(ws + 39845888);    // [4096][1024] bf16  8 MB
  unsigned short* wprojT = (unsigned short*)(ws + 48234496);    // [1024][1024] bf16  2 MB
  unsigned short* PO     = (unsigned short*)(ws + 50331648);    // 2560*4096 bf16    21 MB
  float2*         ML2    = (float2*)(ws + 71303168);            // 2560*64 float2   1.3 MB
  const size_t ws_needed = 71303168 + 1310720;                  // 72.6 MB

  cvt_hidden<<<dim3(4096), dim3(256), 0, stream>>>(hidden, hseq);
  transpose_cvt<<<dim3(32, 96), dim3(256), 0, stream>>>(attn_w, wqkvT, 1024, 3072);
  make_wproj<<<dim3(16, 16), dim3(256), 0, stream>>>(projectors, proj_w, wprojT);
  gemm_bt<0><<<dim3(24, 32), dim3(256), 0, stream>>>(hseq, wqkvT, attn_b, nullptr,
                                                     qb, kb, vb, 4096, 3072, 1024);
  if (ws_size >= ws_needed) {
    attn_partial<<<dim3(32, 32, 4), dim3(128), 0, stream>>>(qb, kb, vb, PO, ML2);
    attn_reduce<<<dim3(32, 32), dim3(256), 0, stream>>>(PO, ML2, attnM);
  } else {
    attn_direct<<<dim3(32, 32), dim3(128), 0, stream>>>(qb, kb, vb, attnM);
  }
  gemm_bt<1><<<dim3(8, 32), dim3(256), 0, stream>>>(attnM, wprojT, proj_b, out,
                                                    nullptr, nullptr, nullptr, 4096, 1024, 1024);
}